// Round 4
// baseline (511.331 us; speedup 1.0000x reference)
//
#include <hip/hip_runtime.h>

typedef __attribute__((ext_vector_type(8))) short bf16x8;
typedef __attribute__((ext_vector_type(8))) unsigned short u16x8;
typedef __attribute__((ext_vector_type(4))) unsigned short u16x4;
typedef __attribute__((ext_vector_type(4))) float f32x4;
typedef unsigned short u16t;

#define MFMA16(a, b, c) __builtin_amdgcn_mfma_f32_16x16x32_bf16((a), (b), (c), 0, 0, 0)
#define GLDS16(gp, lp)                                                        \
  __builtin_amdgcn_global_load_lds(                                           \
      (__attribute__((address_space(1))) void*)(gp),                          \
      (__attribute__((address_space(3))) void*)(lp), 16, 0, 0)

static constexpr float L2E = 1.44269504f;   // log2(e)
static constexpr float MASKV = -1.0e30f;    // finite mask sentinel (no inf paths)
static constexpr float MASKTH = -5.0e29f;   // "is real score" threshold

__device__ __forceinline__ u16t f2b(float f) {
  unsigned u = __builtin_bit_cast(unsigned, f);
  u = u + 0x7fffu + ((u >> 16) & 1u); // RNE
  return (u16t)(u >> 16);
}

// ---------------------------------------------------------------------------
// fp32 -> bf16 conversion of x and the 4 weight matrices, one fused launch.
// ---------------------------------------------------------------------------
__global__ void cvt5(const float* __restrict__ x, const float* __restrict__ wq,
                     const float* __restrict__ wk, const float* __restrict__ wv,
                     const float* __restrict__ wo, u16t* __restrict__ xb,
                     u16t* __restrict__ wqb, u16t* __restrict__ wkb,
                     u16t* __restrict__ wvb, u16t* __restrict__ wob) {
  const int bid = blockIdx.x;
  const float* src; u16t* dst; int gb;
  if (bid < 4096)      { src = x;  dst = xb;  gb = bid; }
  else if (bid < 4608) { src = wq; dst = wqb; gb = bid - 4096; }
  else if (bid < 5120) { src = wk; dst = wkb; gb = bid - 4608; }
  else if (bid < 5632) { src = wv; dst = wvb; gb = bid - 5120; }
  else                 { src = wo; dst = wob; gb = bid - 5632; }
  const size_t i = (size_t)gb * 256 + threadIdx.x; // 8-elem group index
  const float4 a = ((const float4*)src)[2 * i];
  const float4 b = ((const float4*)src)[2 * i + 1];
  u16x8 r;
  r[0] = f2b(a.x); r[1] = f2b(a.y); r[2] = f2b(a.z); r[3] = f2b(a.w);
  r[4] = f2b(b.x); r[5] = f2b(b.y); r[6] = f2b(b.z); r[7] = f2b(b.w);
  *(u16x8*)&dst[8 * i] = r;
}

// ---------------------------------------------------------------------------
// GEMM core (m97 structure). z=2 (V) writes TRANSPOSED output V^T[b][h][hd][s]
// so the attention PV step can read B-fragments directly from global with
// vectorized loads (consecutive keys at fixed hd). 8B u16x4 stores (4
// consecutive s at fixed hd) keep the epilogue coalesced.
// ---------------------------------------------------------------------------
__global__ void gemm_qkv(const u16t* __restrict__ X,
                         const u16t* __restrict__ Wq, const u16t* __restrict__ Wk,
                         const u16t* __restrict__ Wv,
                         const float* __restrict__ bq, const float* __restrict__ bk,
                         const float* __restrict__ bv,
                         u16t* __restrict__ Qo, u16t* __restrict__ Ko,
                         u16t* __restrict__ Vo) {
  __shared__ __align__(16) u16t As[128 * 32];
  __shared__ __align__(16) u16t Bs[128 * 32];
  const int t = threadIdx.x, lane = t & 63, w = t >> 6;
  const int wr = w >> 1, wc = w & 1, m = lane & 15, quad = lane >> 4;
  const int rowBase = blockIdx.y * 128, colBase = blockIdx.x * 128;
  const int z = blockIdx.z;
  const u16t* W = (z == 0) ? Wq : ((z == 1) ? Wk : Wv);
  const float* bias = (z == 0) ? bq : ((z == 1) ? bk : bv);
  u16t* Out = (z == 0) ? Qo : ((z == 1) ? Ko : Vo);

  f32x4 acc[4][4];
#pragma unroll
  for (int i = 0; i < 4; i++)
#pragma unroll
    for (int j = 0; j < 4; j++) acc[i][j] = (f32x4){0.f, 0.f, 0.f, 0.f};

  const int lr = lane >> 2, lc = (lane & 3) * 8;
  for (int kt = 0; kt < 32; ++kt) {
#pragma unroll
    for (int i = 0; i < 2; ++i) {
      const int r0 = i * 64 + w * 16;
      GLDS16(&X[(size_t)(rowBase + r0 + lr) * 1024 + kt * 32 + lc], &As[r0 * 32]);
      GLDS16(&W[(size_t)(colBase + r0 + lr) * 1024 + kt * 32 + lc], &Bs[r0 * 32]);
    }
    __syncthreads();
    bf16x8 af[4], bfr[4];
#pragma unroll
    for (int i = 0; i < 4; i++)
      af[i] = *(const bf16x8*)&As[(wr * 64 + i * 16 + m) * 32 + quad * 8];
#pragma unroll
    for (int j = 0; j < 4; j++)
      bfr[j] = *(const bf16x8*)&Bs[(wc * 64 + j * 16 + m) * 32 + quad * 8];
#pragma unroll
    for (int i = 0; i < 4; i++)
#pragma unroll
      for (int j = 0; j < 4; j++) acc[i][j] = MFMA16(af[i], bfr[j], acc[i][j]);
    __syncthreads();
  }

  const int b_ = rowBase >> 10;          // whole block is in one batch row
  const int sBase = (rowBase & 1023) + wr * 64;
#pragma unroll
  for (int j = 0; j < 4; j++) {
    const int col = colBase + wc * 64 + j * 16 + m;
    const float bv_ = bias[col];
    const int h = col >> 6, hd = col & 63;
    if (z == 2) {
      // V^T: Out[((b*16+h)*64 + hd)*1024 + s], 4 consecutive s per u16x4
#pragma unroll
      for (int i = 0; i < 4; i++) {
        const int s0 = sBase + i * 16 + quad * 4;
        u16x4 pk;
#pragma unroll
        for (int r = 0; r < 4; r++) pk[r] = f2b(acc[i][j][r] + bv_);
        *(u16x4*)&Out[(((size_t)b_ * 16 + h) * 64 + hd) * 1024 + s0] = pk;
      }
    } else {
#pragma unroll
      for (int i = 0; i < 4; i++) {
#pragma unroll
        for (int r = 0; r < 4; r++) {
          const int s_ = sBase + i * 16 + quad * 4 + r;
          const size_t oi = (((size_t)b_ * 16 + h) * 1024 + s_) * 64 + hd;
          Out[oi] = f2b(acc[i][j][r] + bv_);
        }
      }
    }
  }
}

__global__ void gemm_o(const u16t* __restrict__ A, const u16t* __restrict__ W,
                       const float* __restrict__ bias, float* __restrict__ Out) {
  __shared__ __align__(16) u16t As[128 * 32];
  __shared__ __align__(16) u16t Bs[128 * 32];
  const int t = threadIdx.x, lane = t & 63, w = t >> 6;
  const int wr = w >> 1, wc = w & 1, m = lane & 15, quad = lane >> 4;
  const int rowBase = blockIdx.y * 128, colBase = blockIdx.x * 128;

  f32x4 acc[4][4];
#pragma unroll
  for (int i = 0; i < 4; i++)
#pragma unroll
    for (int j = 0; j < 4; j++) acc[i][j] = (f32x4){0.f, 0.f, 0.f, 0.f};

  const int lr = lane >> 2, lc = (lane & 3) * 8;
  for (int kt = 0; kt < 32; ++kt) {
#pragma unroll
    for (int i = 0; i < 2; ++i) {
      const int r0 = i * 64 + w * 16;
      GLDS16(&A[(size_t)(rowBase + r0 + lr) * 1024 + kt * 32 + lc], &As[r0 * 32]);
      GLDS16(&W[(size_t)(colBase + r0 + lr) * 1024 + kt * 32 + lc], &Bs[r0 * 32]);
    }
    __syncthreads();
    bf16x8 af[4], bfr[4];
#pragma unroll
    for (int i = 0; i < 4; i++)
      af[i] = *(const bf16x8*)&As[(wr * 64 + i * 16 + m) * 32 + quad * 8];
#pragma unroll
    for (int j = 0; j < 4; j++)
      bfr[j] = *(const bf16x8*)&Bs[(wc * 64 + j * 16 + m) * 32 + quad * 8];
#pragma unroll
    for (int i = 0; i < 4; i++)
#pragma unroll
      for (int j = 0; j < 4; j++) acc[i][j] = MFMA16(af[i], bfr[j], acc[i][j]);
    __syncthreads();
  }

#pragma unroll
  for (int j = 0; j < 4; j++) {
    const int col = colBase + wc * 64 + j * 16 + m;
    const float bv_ = bias[col];
#pragma unroll
    for (int i = 0; i < 4; i++) {
#pragma unroll
      for (int r = 0; r < 4; r++) {
        const int row = rowBase + wr * 64 + i * 16 + quad * 4 + r;
        Out[(size_t)row * 1024 + col] = acc[i][j][r] + bv_;
      }
    }
  }
}

// ---------------------------------------------------------------------------
// Flash attention v5: BARRIER-FREE main loop (m169 lesson: K/V are L2-fit at
// S=1024 -- LDS staging was pure overhead). K read [key][hd] (natural), V read
// from pre-transposed V^T[b][h][hd][s] (producer-side transpose) -- both as
// direct vectorized global loads; V loads issued before softmax, consumed
// after (~400 cyc hidden). Only LDS: per-wave P round-trip + maskL.
// Grid: 1024 blocks (exactly resident at 4/CU), each does q-tile pair
// (p, 15-p) = uniform 17 tile-iterations. id%8 keeps all 8 blocks of one
// (b,h) on one XCD for K/V L2 sharing. __launch_bounds__(256,4) -> 128 VGPR
// cap (round-3 lesson: default cap was 64 -> scratch spills, 83MB writes).
// ---------------------------------------------------------------------------
__global__ __launch_bounds__(256, 4) void attn(
    const u16t* __restrict__ Q, const u16t* __restrict__ K,
    const u16t* __restrict__ VT, const int* __restrict__ ids,
    u16t* __restrict__ Oo) {
  constexpr int PSTR = 72;
  __shared__ __align__(16) u16t Ps[4][16 * PSTR];
  __shared__ unsigned long long maskL[16];

  const int t = threadIdx.x, lane = t & 63, w = t >> 6;
  const int m = lane & 15, quad = lane >> 4;
  // decode: g = XCD slot, bh = (b,h) pair (all its blocks share g), pair 0..7
  const int id = blockIdx.x;
  const int g = id & 7, j = id >> 3;
  const int bh = g + 8 * (j & 15);
  const int pair = j >> 4;
  const int b = bh >> 4;
  const size_t hoff = (size_t)bh * 65536;   // 1024 * 64

  // ---- pad-key bitmask (one u64 per 64-key tile) ----
#pragma unroll
  for (int c = 0; c < 4; ++c) {
    const int chunk = w * 4 + c;
    const int idv = ids[b * 1024 + chunk * 64 + lane];
    const unsigned long long mk = __ballot(idv != 1);
    if (lane == 0) maskL[chunk] = mk;
  }
  __syncthreads();   // the only block-wide barrier

  u16t* const Pw = &Ps[w][0];

  for (int pass = 0; pass < 2; ++pass) {
    const int qt = pass ? (15 - pair) : pair;
    const int qbase = qt * 64 + w * 16;
    const int qrow0 = qbase + quad * 4; // + r

    const bf16x8 qf0 =
        *(const bf16x8*)&Q[hoff + (size_t)(qbase + m) * 64 + quad * 8];
    const bf16x8 qf1 =
        *(const bf16x8*)&Q[hoff + (size_t)(qbase + m) * 64 + 32 + quad * 8];

    float mi[4], li[4];
    f32x4 o[4];
#pragma unroll
    for (int r = 0; r < 4; r++) { mi[r] = MASKV; li[r] = 0.f; }
#pragma unroll
    for (int ot = 0; ot < 4; ot++) o[ot] = (f32x4){0.f, 0.f, 0.f, 0.f};

    for (int kt = 0; kt <= qt; ++kt) {
      const unsigned long long km = maskL[kt];

      // ---- scores: Q @ K^T over 4 key sub-tiles (K direct from global) ----
      f32x4 sc[4];
      float rowmax[4] = {MASKV, MASKV, MASKV, MASKV};
      bf16x8 kf0[4], kf1[4];
      const int ntmax = (qt == kt) ? ((w >> 2) + ((w & 3) == 3 ? 0 : 0)) : 3;
      (void)ntmax;
#pragma unroll
      for (int nt = 0; nt < 4; nt++) {
        if ((kt * 64 + nt * 16) <= (qbase + 15)) { // wave-uniform causal skip
          const size_t krow = hoff + (size_t)(kt * 64 + nt * 16 + m) * 64;
          kf0[nt] = *(const bf16x8*)&K[krow + quad * 8];
          kf1[nt] = *(const bf16x8*)&K[krow + 32 + quad * 8];
        }
      }
#pragma unroll
      for (int nt = 0; nt < 4; nt++) {
        if ((kt * 64 + nt * 16) <= (qbase + 15)) {
          f32x4 c = (f32x4){0.f, 0.f, 0.f, 0.f};
          c = MFMA16(qf0, kf0[nt], c);
          c = MFMA16(qf1, kf1[nt], c);
          const int key = kt * 64 + nt * 16 + m;
          const bool pv = ((km >> (nt * 16 + m)) & 1ull) != 0;
#pragma unroll
          for (int r = 0; r < 4; r++) {
            const float s = (pv && key <= qrow0 + r) ? c[r] * 0.125f : MASKV;
            sc[nt][r] = s;
            rowmax[r] = fmaxf(rowmax[r], s);
          }
        } else {
#pragma unroll
          for (int r = 0; r < 4; r++) sc[nt][r] = MASKV;
        }
      }

      // ---- issue V^T loads now; consumed after softmax (~400 cyc later) ----
      bf16x8 vv0[4], vv1[4];
#pragma unroll
      for (int ot = 0; ot < 4; ++ot) {
        const size_t vrow = hoff + (size_t)(ot * 16 + m) * 1024 + kt * 64;
        vv0[ot] = *(const bf16x8*)&VT[vrow + quad * 8];
        vv1[ot] = *(const bf16x8*)&VT[vrow + 32 + quad * 8];
      }

      // ---- online softmax ----
#pragma unroll
      for (int r = 0; r < 4; r++) {
        float v_ = rowmax[r];
        v_ = fmaxf(v_, __shfl_xor(v_, 1));
        v_ = fmaxf(v_, __shfl_xor(v_, 2));
        v_ = fmaxf(v_, __shfl_xor(v_, 4));
        v_ = fmaxf(v_, __shfl_xor(v_, 8));
        rowmax[r] = v_;
      }
      float alpha[4], rsum[4];
#pragma unroll
      for (int r = 0; r < 4; r++) {
        const float mn = fmaxf(mi[r], rowmax[r]);
        alpha[r] = exp2f((mi[r] - mn) * L2E); // finite arg; underflows to 0
        mi[r] = mn;
        rsum[r] = 0.f;
      }
#pragma unroll
      for (int nt = 0; nt < 4; nt++) {
#pragma unroll
        for (int r = 0; r < 4; r++) {
          const float p =
              (sc[nt][r] > MASKTH) ? exp2f((sc[nt][r] - mi[r]) * L2E) : 0.f;
          rsum[r] += p;
          Pw[(quad * 4 + r) * PSTR + nt * 16 + m] = f2b(p);
        }
      }
#pragma unroll
      for (int r = 0; r < 4; r++) {
        float v_ = rsum[r];
        v_ += __shfl_xor(v_, 1);
        v_ += __shfl_xor(v_, 2);
        v_ += __shfl_xor(v_, 4);
        v_ += __shfl_xor(v_, 8);
        li[r] = li[r] * alpha[r] + v_;
      }
#pragma unroll
      for (int ot = 0; ot < 4; ot++)
#pragma unroll
        for (int r = 0; r < 4; r++) o[ot][r] *= alpha[r];

      // ---- P @ V (P via per-wave LDS round-trip; V already in regs) ----
      const bf16x8 p0 = *(const bf16x8*)&Pw[m * PSTR + quad * 8];
      const bf16x8 p1 = *(const bf16x8*)&Pw[m * PSTR + 32 + quad * 8];
#pragma unroll
      for (int ot = 0; ot < 4; ot++) {
        o[ot] = MFMA16(p0, vv0[ot], o[ot]);
        o[ot] = MFMA16(p1, vv1[ot], o[ot]);
      }
    }

    // ---- write attn output [B,S,D] with D-index = h*64 + hd (bf16, ws) ----
    const int h = bh & 15;
#pragma unroll
    for (int r = 0; r < 4; r++) {
      const float inv = li[r] > 1e-30f ? 1.f / li[r] : 0.f;
      const int q = qbase + quad * 4 + r;
#pragma unroll
      for (int ot = 0; ot < 4; ot++) {
        const int col = h * 64 + ot * 16 + m;
        Oo[((size_t)(b * 1024 + q)) * 1024 + col] = f2b(o[ot][r] * inv);
      }
    }
  }
}

// ---------------------------------------------------------------------------
extern "C" void kernel_launch(void* const* d_in, const int* in_sizes, int n_in,
                              void* d_out, int out_size, void* d_ws, size_t ws_size,
                              hipStream_t stream) {
  const float* x  = (const float*)d_in[0];
  const int*   ids = (const int*)d_in[1];
  const float* Wq = (const float*)d_in[2];
  const float* bq = (const float*)d_in[3];
  const float* Wk = (const float*)d_in[4];
  const float* bk = (const float*)d_in[5];
  const float* Wv = (const float*)d_in[6];
  const float* bv = (const float*)d_in[7];
  const float* Wo = (const float*)d_in[8];
  const float* bo = (const float*)d_in[9];
  float* out = (float*)d_out;

  // ws layout (bf16 elems): XB 8.4M | WqB,WkB,WvB,WoB 1M each | Q,K,V 8.4M each
  u16t* XB  = (u16t*)d_ws;
  u16t* WqB = XB  + 8388608;
  u16t* WkB = WqB + 1048576;
  u16t* WvB = WkB + 1048576;
  u16t* WoB = WvB + 1048576;
  u16t* Qw  = WoB + 1048576;
  u16t* Kw  = Qw  + 8388608;
  u16t* Vw  = Kw  + 8388608;   // holds V^T[b][h][hd][s]
  u16t* AO  = XB; // reuse after gemm_qkv consumed XB

  cvt5<<<6144, 256, 0, stream>>>(x, Wq, Wk, Wv, Wo, XB, WqB, WkB, WvB, WoB);
  gemm_qkv<<<dim3(8, 64, 3), 256, 0, stream>>>(XB, WqB, WkB, WvB, bq, bk, bv,
                                               Qw, Kw, Vw);
  attn<<<1024, 256, 0, stream>>>(Qw, Kw, Vw, ids, AO);
  gemm_o<<<dim3(8, 64, 1), 256, 0, stream>>>(AO, WoB, bo, out);
}

// Round 5
// 354.533 us; speedup vs baseline: 1.4423x; 1.4423x over previous
//
#include <hip/hip_runtime.h>

typedef __attribute__((ext_vector_type(8))) short bf16x8;
typedef __attribute__((ext_vector_type(8))) unsigned short u16x8;
typedef __attribute__((ext_vector_type(4))) unsigned short u16x4;
typedef __attribute__((ext_vector_type(4))) float f32x4;
typedef unsigned short u16t;

#define MFMA16(a, b, c) __builtin_amdgcn_mfma_f32_16x16x32_bf16((a), (b), (c), 0, 0, 0)
#define GLDS16(gp, lp)                                                        \
  __builtin_amdgcn_global_load_lds(                                           \
      (__attribute__((address_space(1))) void*)(gp),                          \
      (__attribute__((address_space(3))) void*)(lp), 16, 0, 0)

static constexpr float L2E = 1.44269504f;   // log2(e)
static constexpr float MASKV = -1.0e30f;    // finite mask sentinel (no inf paths)
static constexpr float MASKTH = -5.0e29f;   // "is real score" threshold

__device__ __forceinline__ u16t f2b(float f) {
  unsigned u = __builtin_bit_cast(unsigned, f);
  u = u + 0x7fffu + ((u >> 16) & 1u); // RNE
  return (u16t)(u >> 16);
}

// ---------------------------------------------------------------------------
// fp32 -> bf16 conversion of x and the 4 weight matrices, one fused launch.
// ---------------------------------------------------------------------------
__global__ void cvt5(const float* __restrict__ x, const float* __restrict__ wq,
                     const float* __restrict__ wk, const float* __restrict__ wv,
                     const float* __restrict__ wo, u16t* __restrict__ xb,
                     u16t* __restrict__ wqb, u16t* __restrict__ wkb,
                     u16t* __restrict__ wvb, u16t* __restrict__ wob) {
  const int bid = blockIdx.x;
  const float* src; u16t* dst; int gb;
  if (bid < 4096)      { src = x;  dst = xb;  gb = bid; }
  else if (bid < 4608) { src = wq; dst = wqb; gb = bid - 4096; }
  else if (bid < 5120) { src = wk; dst = wkb; gb = bid - 4608; }
  else if (bid < 5632) { src = wv; dst = wvb; gb = bid - 5120; }
  else                 { src = wo; dst = wob; gb = bid - 5632; }
  const size_t i = (size_t)gb * 256 + threadIdx.x; // 8-elem group index
  const float4 a = ((const float4*)src)[2 * i];
  const float4 b = ((const float4*)src)[2 * i + 1];
  u16x8 r;
  r[0] = f2b(a.x); r[1] = f2b(a.y); r[2] = f2b(a.z); r[3] = f2b(a.w);
  r[4] = f2b(b.x); r[5] = f2b(b.y); r[6] = f2b(b.z); r[7] = f2b(b.w);
  *(u16x8*)&dst[8 * i] = r;
}

// ---------------------------------------------------------------------------
// GEMM core (m97 structure). z=2 (V) writes TRANSPOSED output V^T[b][h][hd][s]
// so the attention PV step reads B-fragments directly from global with
// vectorized loads. (Unchanged from round 4 -- passed.)
// ---------------------------------------------------------------------------
__global__ void gemm_qkv(const u16t* __restrict__ X,
                         const u16t* __restrict__ Wq, const u16t* __restrict__ Wk,
                         const u16t* __restrict__ Wv,
                         const float* __restrict__ bq, const float* __restrict__ bk,
                         const float* __restrict__ bv,
                         u16t* __restrict__ Qo, u16t* __restrict__ Ko,
                         u16t* __restrict__ Vo) {
  __shared__ __align__(16) u16t As[128 * 32];
  __shared__ __align__(16) u16t Bs[128 * 32];
  const int t = threadIdx.x, lane = t & 63, w = t >> 6;
  const int wr = w >> 1, wc = w & 1, m = lane & 15, quad = lane >> 4;
  const int rowBase = blockIdx.y * 128, colBase = blockIdx.x * 128;
  const int z = blockIdx.z;
  const u16t* W = (z == 0) ? Wq : ((z == 1) ? Wk : Wv);
  const float* bias = (z == 0) ? bq : ((z == 1) ? bk : bv);
  u16t* Out = (z == 0) ? Qo : ((z == 1) ? Ko : Vo);

  f32x4 acc[4][4];
#pragma unroll
  for (int i = 0; i < 4; i++)
#pragma unroll
    for (int j = 0; j < 4; j++) acc[i][j] = (f32x4){0.f, 0.f, 0.f, 0.f};

  const int lr = lane >> 2, lc = (lane & 3) * 8;
  for (int kt = 0; kt < 32; ++kt) {
#pragma unroll
    for (int i = 0; i < 2; ++i) {
      const int r0 = i * 64 + w * 16;
      GLDS16(&X[(size_t)(rowBase + r0 + lr) * 1024 + kt * 32 + lc], &As[r0 * 32]);
      GLDS16(&W[(size_t)(colBase + r0 + lr) * 1024 + kt * 32 + lc], &Bs[r0 * 32]);
    }
    __syncthreads();
    bf16x8 af[4], bfr[4];
#pragma unroll
    for (int i = 0; i < 4; i++)
      af[i] = *(const bf16x8*)&As[(wr * 64 + i * 16 + m) * 32 + quad * 8];
#pragma unroll
    for (int j = 0; j < 4; j++)
      bfr[j] = *(const bf16x8*)&Bs[(wc * 64 + j * 16 + m) * 32 + quad * 8];
#pragma unroll
    for (int i = 0; i < 4; i++)
#pragma unroll
      for (int j = 0; j < 4; j++) acc[i][j] = MFMA16(af[i], bfr[j], acc[i][j]);
    __syncthreads();
  }

  const int b_ = rowBase >> 10;          // whole block is in one batch row
  const int sBase = (rowBase & 1023) + wr * 64;
#pragma unroll
  for (int j = 0; j < 4; j++) {
    const int col = colBase + wc * 64 + j * 16 + m;
    const float bv_ = bias[col];
    const int h = col >> 6, hd = col & 63;
    if (z == 2) {
      // V^T: Out[((b*16+h)*64 + hd)*1024 + s], 4 consecutive s per u16x4
#pragma unroll
      for (int i = 0; i < 4; i++) {
        const int s0 = sBase + i * 16 + quad * 4;
        u16x4 pk;
#pragma unroll
        for (int r = 0; r < 4; r++) pk[r] = f2b(acc[i][j][r] + bv_);
        *(u16x4*)&Out[(((size_t)b_ * 16 + h) * 64 + hd) * 1024 + s0] = pk;
      }
    } else {
#pragma unroll
      for (int i = 0; i < 4; i++) {
#pragma unroll
        for (int r = 0; r < 4; r++) {
          const int s_ = sBase + i * 16 + quad * 4 + r;
          const size_t oi = (((size_t)b_ * 16 + h) * 1024 + s_) * 64 + hd;
          Out[oi] = f2b(acc[i][j][r] + bv_);
        }
      }
    }
  }
}

__global__ void gemm_o(const u16t* __restrict__ A, const u16t* __restrict__ W,
                       const float* __restrict__ bias, float* __restrict__ Out) {
  __shared__ __align__(16) u16t As[128 * 32];
  __shared__ __align__(16) u16t Bs[128 * 32];
  const int t = threadIdx.x, lane = t & 63, w = t >> 6;
  const int wr = w >> 1, wc = w & 1, m = lane & 15, quad = lane >> 4;
  const int rowBase = blockIdx.y * 128, colBase = blockIdx.x * 128;

  f32x4 acc[4][4];
#pragma unroll
  for (int i = 0; i < 4; i++)
#pragma unroll
    for (int j = 0; j < 4; j++) acc[i][j] = (f32x4){0.f, 0.f, 0.f, 0.f};

  const int lr = lane >> 2, lc = (lane & 3) * 8;
  for (int kt = 0; kt < 32; ++kt) {
#pragma unroll
    for (int i = 0; i < 2; ++i) {
      const int r0 = i * 64 + w * 16;
      GLDS16(&A[(size_t)(rowBase + r0 + lr) * 1024 + kt * 32 + lc], &As[r0 * 32]);
      GLDS16(&W[(size_t)(colBase + r0 + lr) * 1024 + kt * 32 + lc], &Bs[r0 * 32]);
    }
    __syncthreads();
    bf16x8 af[4], bfr[4];
#pragma unroll
    for (int i = 0; i < 4; i++)
      af[i] = *(const bf16x8*)&As[(wr * 64 + i * 16 + m) * 32 + quad * 8];
#pragma unroll
    for (int j = 0; j < 4; j++)
      bfr[j] = *(const bf16x8*)&Bs[(wc * 64 + j * 16 + m) * 32 + quad * 8];
#pragma unroll
    for (int i = 0; i < 4; i++)
#pragma unroll
      for (int j = 0; j < 4; j++) acc[i][j] = MFMA16(af[i], bfr[j], acc[i][j]);
    __syncthreads();
  }

#pragma unroll
  for (int j = 0; j < 4; j++) {
    const int col = colBase + wc * 64 + j * 16 + m;
    const float bv_ = bias[col];
#pragma unroll
    for (int i = 0; i < 4; i++) {
#pragma unroll
      for (int r = 0; r < 4; r++) {
        const int row = rowBase + wr * 64 + i * 16 + quad * 4 + r;
        Out[(size_t)row * 1024 + col] = acc[i][j][r] + bv_;
      }
    }
  }
}

// ---------------------------------------------------------------------------
// Flash attention v6: TLP over prefetch.
//  - 1024 blocks x 512 thr (8 waves). Waves 0-3 handle qt=pair, waves 4-7
//    handle qt=15-pair  -> every block is exactly 68 wave-tile-iterations
//    (uniform, no tail), 4 blocks/CU resident = 32 waves/CU = 8 waves/SIMD.
//  - Barrier-free main loop (only barrier: maskL prologue). K from global
//    [key][hd]; V from producer-transposed V^T[b][h][hd][s]. All loads are
//    immediate-use: live set ~56 VGPR -> fits the compiler's 64-VGPR budget
//    with ZERO spills (rounds 3/4 lesson: >56 live regs => scratch traffic,
//    99MB..566MB of WRITE_SIZE garbage).
//  - Latency hidden by 8 waves/SIMD interleaving, not per-wave prefetch.
// ---------------------------------------------------------------------------
__global__ __launch_bounds__(512) void attn(
    const u16t* __restrict__ Q, const u16t* __restrict__ K,
    const u16t* __restrict__ VT, const int* __restrict__ ids,
    u16t* __restrict__ Oo) {
  constexpr int PSTR = 72;
  __shared__ __align__(16) u16t Ps[8][16 * PSTR];
  __shared__ unsigned long long maskL[16];

  const int t = threadIdx.x, lane = t & 63, w = t >> 6;   // w: 0..7
  const int m = lane & 15, quad = lane >> 4;
  const int id = blockIdx.x;
  const int bh = id >> 3, pair = id & 7;
  const int b = bh >> 4, h = bh & 15;
  const size_t hoff = (size_t)bh * 65536;   // 1024 * 64

  const int group = w >> 2, wl = w & 3;
  const int qt = group ? (15 - pair) : pair;
  const int qbase = qt * 64 + wl * 16;
  const int qrow0 = qbase + quad * 4; // + r

  // ---- pad-key bitmask (one u64 per 64-key tile) ----
#pragma unroll
  for (int c = 0; c < 2; ++c) {
    const int chunk = w * 2 + c;
    const int idv = ids[b * 1024 + chunk * 64 + lane];
    const unsigned long long mk = __ballot(idv != 1);
    if (lane == 0) maskL[chunk] = mk;
  }
  __syncthreads();   // the only block-wide barrier

  u16t* const Pw = &Ps[w][0];

  const bf16x8 qf0 =
      *(const bf16x8*)&Q[hoff + (size_t)(qbase + m) * 64 + quad * 8];
  const bf16x8 qf1 =
      *(const bf16x8*)&Q[hoff + (size_t)(qbase + m) * 64 + 32 + quad * 8];

  float mi[4], li[4];
  f32x4 o[4];
#pragma unroll
  for (int r = 0; r < 4; r++) { mi[r] = MASKV; li[r] = 0.f; }
#pragma unroll
  for (int ot = 0; ot < 4; ot++) o[ot] = (f32x4){0.f, 0.f, 0.f, 0.f};

  for (int kt = 0; kt <= qt; ++kt) {
    const unsigned long long km = maskL[kt];

    // ---- scores: Q @ K^T over 4 key sub-tiles (K immediate-use) ----
    f32x4 sc[4];
    float rowmax[4] = {MASKV, MASKV, MASKV, MASKV};
#pragma unroll
    for (int nt = 0; nt < 4; nt++) {
      if ((kt * 64 + nt * 16) <= (qbase + 15)) { // wave-uniform causal skip
        const size_t krow = hoff + (size_t)(kt * 64 + nt * 16 + m) * 64;
        const bf16x8 k0 = *(const bf16x8*)&K[krow + quad * 8];
        const bf16x8 k1 = *(const bf16x8*)&K[krow + 32 + quad * 8];
        f32x4 c = (f32x4){0.f, 0.f, 0.f, 0.f};
        c = MFMA16(qf0, k0, c);
        c = MFMA16(qf1, k1, c);
        const int key = kt * 64 + nt * 16 + m;
        const bool pv = ((km >> (nt * 16 + m)) & 1ull) != 0;
#pragma unroll
        for (int r = 0; r < 4; r++) {
          const float s = (pv && key <= qrow0 + r) ? c[r] * 0.125f : MASKV;
          sc[nt][r] = s;
          rowmax[r] = fmaxf(rowmax[r], s);
        }
      } else {
#pragma unroll
        for (int r = 0; r < 4; r++) sc[nt][r] = MASKV;
      }
    }

    // ---- online softmax ----
#pragma unroll
    for (int r = 0; r < 4; r++) {
      float v_ = rowmax[r];
      v_ = fmaxf(v_, __shfl_xor(v_, 1));
      v_ = fmaxf(v_, __shfl_xor(v_, 2));
      v_ = fmaxf(v_, __shfl_xor(v_, 4));
      v_ = fmaxf(v_, __shfl_xor(v_, 8));
      rowmax[r] = v_;
    }
    float alpha[4], rsum[4];
#pragma unroll
    for (int r = 0; r < 4; r++) {
      const float mn = fmaxf(mi[r], rowmax[r]);
      alpha[r] = exp2f((mi[r] - mn) * L2E); // finite arg; underflows to 0
      mi[r] = mn;
      rsum[r] = 0.f;
    }
#pragma unroll
    for (int nt = 0; nt < 4; nt++) {
#pragma unroll
      for (int r = 0; r < 4; r++) {
        const float p =
            (sc[nt][r] > MASKTH) ? exp2f((sc[nt][r] - mi[r]) * L2E) : 0.f;
        rsum[r] += p;
        Pw[(quad * 4 + r) * PSTR + nt * 16 + m] = f2b(p);
      }
    }
#pragma unroll
    for (int r = 0; r < 4; r++) {
      float v_ = rsum[r];
      v_ += __shfl_xor(v_, 1);
      v_ += __shfl_xor(v_, 2);
      v_ += __shfl_xor(v_, 4);
      v_ += __shfl_xor(v_, 8);
      li[r] = li[r] * alpha[r] + v_;
    }
#pragma unroll
    for (int ot = 0; ot < 4; ot++)
#pragma unroll
      for (int r = 0; r < 4; r++) o[ot][r] *= alpha[r];

    // ---- P @ V (P via per-wave LDS round-trip; V^T immediate-use) ----
    const bf16x8 p0 = *(const bf16x8*)&Pw[m * PSTR + quad * 8];
    const bf16x8 p1 = *(const bf16x8*)&Pw[m * PSTR + 32 + quad * 8];
#pragma unroll
    for (int ot = 0; ot < 4; ot++) {
      const size_t vrow = hoff + (size_t)(ot * 16 + m) * 1024 + kt * 64;
      const bf16x8 v0 = *(const bf16x8*)&VT[vrow + quad * 8];
      const bf16x8 v1 = *(const bf16x8*)&VT[vrow + 32 + quad * 8];
      o[ot] = MFMA16(p0, v0, o[ot]);
      o[ot] = MFMA16(p1, v1, o[ot]);
    }
  }

  // ---- write attn output [B,S,D] with D-index = h*64 + hd (bf16, ws) ----
#pragma unroll
  for (int r = 0; r < 4; r++) {
    const float inv = li[r] > 1e-30f ? 1.f / li[r] : 0.f;
    const int q = qbase + quad * 4 + r;
#pragma unroll
    for (int ot = 0; ot < 4; ot++) {
      const int col = h * 64 + ot * 16 + m;
      Oo[((size_t)(b * 1024 + q)) * 1024 + col] = f2b(o[ot][r] * inv);
    }
  }
}

// ---------------------------------------------------------------------------
extern "C" void kernel_launch(void* const* d_in, const int* in_sizes, int n_in,
                              void* d_out, int out_size, void* d_ws, size_t ws_size,
                              hipStream_t stream) {
  const float* x  = (const float*)d_in[0];
  const int*   ids = (const int*)d_in[1];
  const float* Wq = (const float*)d_in[2];
  const float* bq = (const float*)d_in[3];
  const float* Wk = (const float*)d_in[4];
  const float* bk = (const float*)d_in[5];
  const float* Wv = (const float*)d_in[6];
  const float* bv = (const float*)d_in[7];
  const float* Wo = (const float*)d_in[8];
  const float* bo = (const float*)d_in[9];
  float* out = (float*)d_out;

  // ws layout (bf16 elems): XB 8.4M | WqB,WkB,WvB,WoB 1M each | Q,K,V 8.4M each
  u16t* XB  = (u16t*)d_ws;
  u16t* WqB = XB  + 8388608;
  u16t* WkB = WqB + 1048576;
  u16t* WvB = WkB + 1048576;
  u16t* WoB = WvB + 1048576;
  u16t* Qw  = WoB + 1048576;
  u16t* Kw  = Qw  + 8388608;
  u16t* Vw  = Kw  + 8388608;   // holds V^T[b][h][hd][s]
  u16t* AO  = XB; // reuse after gemm_qkv consumed XB

  cvt5<<<6144, 256, 0, stream>>>(x, Wq, Wk, Wv, Wo, XB, WqB, WkB, WvB, WoB);
  gemm_qkv<<<dim3(8, 64, 3), 256, 0, stream>>>(XB, WqB, WkB, WvB, bq, bk, bv,
                                               Qw, Kw, Vw);
  attn<<<1024, 512, 0, stream>>>(Qw, Kw, Vw, ids, AO);
  gemm_o<<<dim3(8, 64, 1), 256, 0, stream>>>(AO, WoB, bo, out);
}